// Round 6
// baseline (280.773 us; speedup 1.0000x reference)
//
#include <hip/hip_runtime.h>
#include <stdint.h>

// Problem constants
#define B_SZ 32
#define F_SZ 40
#define NB_SZ 36
#define R_SZ 512
#define H_SZ 512
#define D_SZ 1536
#define M1 (B_SZ * F_SZ * NB_SZ)   // 46080
#define NROW (B_SZ * F_SZ)         // 1280
#define FNB (F_SZ * NB_SZ)         // 1440

typedef __attribute__((ext_vector_type(8))) short short8;   // 8 bf16 (MFMA A/B frag)
typedef __attribute__((ext_vector_type(4))) float f32x4;    // MFMA C/D frag

__device__ __forceinline__ unsigned short f2bf(float f) {
    unsigned int x = __float_as_uint(f);
    return (unsigned short)((x + 0x7fffu + ((x >> 16) & 1u)) >> 16);  // RNE
}
__device__ __forceinline__ float bf2f(unsigned short u) {
    union { unsigned int i; float f; } v; v.i = ((unsigned int)u) << 16; return v.f;
}
__device__ __forceinline__ unsigned int cvtpk(float lo, float hi) {
    unsigned int r;
    asm("v_cvt_pk_bf16_f32 %0, %1, %2" : "=v"(r) : "v"(lo), "v"(hi));
    return r;
}
__device__ __forceinline__ float fast_rcp(float x) {
    float r; asm("v_rcp_f32 %0, %1" : "=v"(r) : "v"(x)); return r;
}
// tanh(x) = 1 - 2/(exp2(2*log2e*x)+1). Saturates correctly at +/-inf exp2.
__device__ __forceinline__ float fast_tanh(float x) {
    float t = __builtin_amdgcn_exp2f(2.8853900817779268f * x);
    return 1.0f - 2.0f * fast_rcp(t + 1.0f);
}

// direct-to-LDS 16B DMA: wave-uniform LDS base + lane*16; per-lane global src
__device__ __forceinline__ void gload_lds16(const void* gsrc, void* ldst) {
    __builtin_amdgcn_global_load_lds(
        (const __attribute__((address_space(1))) unsigned int*)gsrc,
        (__attribute__((address_space(3))) unsigned int*)ldst, 16, 0, 0);
}

// ---------------------------------------------------------------------------
// merged: blocks 0..255 -> hproj; blocks 256..383 -> Wsb = bf16(Wsf)
// ---------------------------------------------------------------------------
__global__ __launch_bounds__(256) void k_pre(
    const float* __restrict__ hidden,
    const float* __restrict__ Wsh, const float* __restrict__ bsh,
    const float* __restrict__ bsf,
    const float* __restrict__ Wrh, const float* __restrict__ brh,
    const float* __restrict__ brf,
    float* __restrict__ hs, float* __restrict__ hr,
    const float* __restrict__ Wsf, unsigned short* __restrict__ Wsb)
{
    const int t = threadIdx.x;
    if (blockIdx.x >= 256) {
        int i = ((blockIdx.x - 256) * 256 + t) * 8;
        float4 f0 = *(const float4*)(Wsf + i);
        float4 f1 = *(const float4*)(Wsf + i + 4);
        uint4 pk = {cvtpk(f0.x, f0.y), cvtpk(f0.z, f0.w),
                    cvtpk(f1.x, f1.y), cvtpk(f1.z, f1.w)};
        *(uint4*)(Wsb + i) = pk;
        return;
    }
    __shared__ float hid[H_SZ];
    const int b = blockIdx.x >> 3, hc = blockIdx.x & 7;
    for (int i = t; i < H_SZ; i += 256) hid[i] = hidden[b * H_SZ + i];
    __syncthreads();
    const int h = hc * 64 + (t >> 2), kq = t & 3;
    const float* r1 = Wsh + (size_t)h * H_SZ + kq * 128;
    const float* r2 = Wrh + (size_t)h * H_SZ + kq * 128;
    const float* hh = hid + kq * 128;
    float a1 = 0.f, a2 = 0.f;
    for (int k = 0; k < 128; k += 4) {
        float4 v1 = *(const float4*)(r1 + k);
        float4 v2 = *(const float4*)(r2 + k);
        a1 += hh[k] * v1.x + hh[k+1] * v1.y + hh[k+2] * v1.z + hh[k+3] * v1.w;
        a2 += hh[k] * v2.x + hh[k+1] * v2.y + hh[k+2] * v2.z + hh[k+3] * v2.w;
    }
    a1 += __shfl_xor(a1, 1); a1 += __shfl_xor(a1, 2);
    a2 += __shfl_xor(a2, 1); a2 += __shfl_xor(a2, 2);
    if (kq == 0) {
        hs[b * H_SZ + h] = a1 + bsh[h] + bsf[h];
        hr[b * H_SZ + h] = a2 + brh[h] + brf[h];
    }
}

// ---------------------------------------------------------------------------
// e1 partials: block = 128 m x 256 h (by-half), 512 threads (8 waves, 4mx2h),
// K-outer (8 x BK=64), hp-subtiles of 128 h. acc[2][8] = 64 VGPR.
// A: fp32->bf16 reg-staged, dbuf; B: bf16 via global_load_lds, dbuf.
// Staged traffic: A 189MB + B 189MB (was 189+378).
// e1p[by][m] = sum_{h in half} tanh(S[m,h] + hs[b(m),h]) * was[h]
// ---------------------------------------------------------------------------
__global__ __launch_bounds__(512, 2) void k_e1_mfma(
    const float* __restrict__ feats,        // (46080, 512) fp32
    const unsigned short* __restrict__ Wsb, // (512, 512) bf16
    const float* __restrict__ was,
    const float* __restrict__ hs,
    float* __restrict__ e1p)                // (2, 46080) fp32
{
    __shared__ __align__(16) unsigned char As[2][128 * 128];   // 16 KB each
    __shared__ __align__(16) unsigned char Bs[2][128 * 128];   // 16 KB each
    __shared__ float hsl[2][256];
    __shared__ float wasl[256];
    __shared__ float eps[2][128];

    // bijective XCD swizzle: 720 = 8*90; by-siblings adjacent on one XCD
    const int bx = blockIdx.x;
    const int wid = (bx & 7) * 90 + (bx >> 3);
    const int mb = wid >> 1, by = wid & 1;
    const int m0 = mb * 128, hb = by * 256;
    const int t = threadIdx.x;
    const int b0 = m0 / FNB, b1 = (m0 + 127) / FNB;
    const int thr = (b0 + 1) * FNB - m0;   // local rows >= thr belong to b1

    if (t < 256) {
        hsl[0][t] = hs[b0 * H_SZ + hb + t];
        hsl[1][t] = hs[b1 * H_SZ + hb + t];
        wasl[t]   = was[hb + t];
    }

    const int lane = t & 63, w = t >> 6;
    const int wr = w >> 1, wc = w & 1;     // wave: 32m (wr 0..3) x 64h (wc) per hp
    const int l15 = lane & 15, lk = lane >> 4;

    int ar[2], brw[4];
#pragma unroll
    for (int i = 0; i < 2; i++) ar[i] = wr * 32 + i * 16 + l15;
#pragma unroll
    for (int j = 0; j < 4; j++) brw[j] = wc * 64 + j * 16 + l15;

    const int srow = t >> 3;          // 0..63
    const int wub  = (t & 448) * 16;  // wave-uniform LDS sub-base (w*1024)

    float4 alo[2], ahi[2];
    f32x4 acc[2][8] = {};
    float ep[2][4] = {{0.f}};

    // A tile 128r x 64k fp32: 1024 chunks of 8 elems; cid = it*512+t, it<2
#define E1_LOAD_A(K0) do { \
    _Pragma("unroll") \
    for (int it = 0; it < 2; it++) { \
        int cid = it * 512 + t; \
        int r = cid >> 3, c = cid & 7; \
        const float* src = feats + (size_t)(m0 + r) * R_SZ + (K0) + c * 8; \
        alo[it] = *(const float4*)src; \
        ahi[it] = *(const float4*)(src + 4); \
    } } while (0)

#define E1_WRITE_A(AB) do { \
    _Pragma("unroll") \
    for (int it = 0; it < 2; it++) { \
        int cid = it * 512 + t; \
        int r = cid >> 3, c = cid & 7; \
        uint4 pk = {cvtpk(alo[it].x, alo[it].y), cvtpk(alo[it].z, alo[it].w), \
                    cvtpk(ahi[it].x, ahi[it].y), cvtpk(ahi[it].z, ahi[it].w)}; \
        *(uint4*)(&As[AB][r * 128 + ((c ^ (r & 7)) << 4)]) = pk; \
    } } while (0)

    // B tile 128h x 64k bf16 = 1024 x 16B chunks; it<2; r = it*64 + srow
#define E1_STAGE_B(BUF, HP, K0) do { \
    _Pragma("unroll") \
    for (int it = 0; it < 2; it++) { \
        int r = it * 64 + srow; \
        int gc = (t & 7) ^ (r & 7); \
        gload_lds16(Wsb + (size_t)(hb + (HP) * 128 + r) * R_SZ + (K0) + gc * 8, \
                    &Bs[BUF][it * 8192 + wub]); \
    } } while (0)

#define E1_COMPUTE(HP, BB, AB) do { \
    _Pragma("unroll") \
    for (int ks = 0; ks < 2; ks++) { \
        short8 a[2], bv[4]; \
        int c = ks * 4 + lk; \
        _Pragma("unroll") \
        for (int i = 0; i < 2; i++) \
            a[i] = *(const short8*)(&As[AB][ar[i] * 128 + ((c ^ (ar[i] & 7)) << 4)]); \
        _Pragma("unroll") \
        for (int j = 0; j < 4; j++) \
            bv[j] = *(const short8*)(&Bs[BB][brw[j] * 128 + ((c ^ (brw[j] & 7)) << 4)]); \
        _Pragma("unroll") \
        for (int i = 0; i < 2; i++) \
        _Pragma("unroll") \
        for (int j = 0; j < 4; j++) \
            acc[i][(HP) * 4 + j] = __builtin_amdgcn_mfma_f32_16x16x32_bf16( \
                a[i], bv[j], acc[i][(HP) * 4 + j], 0, 0, 0); \
    } } while (0)

    // prologue: A(ki=0) -> As[0]; B(ki=0,hp=0) -> Bs[0]
    E1_LOAD_A(0);
    E1_STAGE_B(0, 0, 0);
    E1_WRITE_A(0);
    __syncthreads();

    for (int ki = 0; ki < 8; ki++) {
        const int ab = ki & 1;
        // ---- hp = 0 ----
        E1_STAGE_B(1, 1, ki * 64);          // prefetch hp=1 tile of this ki
        if (ki < 7) E1_LOAD_A((ki + 1) * 64);
        E1_COMPUTE(0, 0, ab);
        __syncthreads();
        // ---- hp = 1 ----
        if (ki < 7) E1_STAGE_B(0, 0, (ki + 1) * 64);  // prefetch next-ki hp0
        E1_COMPUTE(1, 1, ab);
        if (ki < 7) E1_WRITE_A(ab ^ 1);
        __syncthreads();
    }

    // epilogue: tanh + was-weighted row partials over 256 h of this half
#pragma unroll
    for (int jj = 0; jj < 8; jj++) {
        int hl = (jj >> 2) * 128 + wc * 64 + (jj & 3) * 16 + l15;
        float wv = wasl[hl];
#pragma unroll
        for (int i = 0; i < 2; i++) {
#pragma unroll
            for (int q = 0; q < 4; q++) {
                int r = wr * 32 + i * 16 + lk * 4 + q;
                float hv = hsl[r >= thr ? 1 : 0][hl];
                ep[i][q] += fast_tanh(acc[i][jj][q] + hv) * wv;
            }
        }
    }
#pragma unroll
    for (int i = 0; i < 2; i++)
#pragma unroll
        for (int q = 0; q < 4; q++) {
            float v = ep[i][q];
            v += __shfl_xor(v, 1);
            v += __shfl_xor(v, 2);
            v += __shfl_xor(v, 4);
            v += __shfl_xor(v, 8);
            if (l15 == 0) eps[wc][wr * 32 + i * 16 + lk * 4 + q] = v;
        }
    __syncthreads();
    if (t < 128) e1p[(size_t)by * M1 + m0 + t] = eps[0][t] + eps[1][t];
#undef E1_LOAD_A
#undef E1_WRITE_A
#undef E1_STAGE_B
#undef E1_COMPUTE
}

// ---------------------------------------------------------------------------
// per n-pair: softmax over 36 e1's (2 partials), att = alpha-weighted sum of
// feats rows (float4 loads), feat[n] = [att(512) | i3d(1024)] bf16. 640 blocks.
// ---------------------------------------------------------------------------
__global__ __launch_bounds__(256) void k_softatt(
    const float* __restrict__ feats,
    const float* __restrict__ i3d,
    const float* __restrict__ e1p,
    unsigned short* __restrict__ feat)
{
    __shared__ float alpha[2][NB_SZ];
    const int n0 = blockIdx.x * 2;
    const int t = threadIdx.x;
    const int w = t >> 6;

    if (w < 2) {
        const int n = n0 + w, lane = t & 63;
        float v = -1e30f;
        if (lane < NB_SZ) {
            int idx = n * NB_SZ + lane;
            v = e1p[idx] + e1p[M1 + idx];
        }
        float m = v;
#pragma unroll
        for (int off = 32; off; off >>= 1) m = fmaxf(m, __shfl_xor(m, off));
        float ex = (lane < NB_SZ) ? __expf(v - m) : 0.f;
        float ssum = ex;
#pragma unroll
        for (int off = 32; off; off >>= 1) ssum += __shfl_xor(ssum, off);
        if (lane < NB_SZ) alpha[w][lane] = ex / ssum;
    }
    __syncthreads();

    const int g = t >> 7, lc = t & 127;
    const int n = n0 + g;
    float4 a4 = {0.f, 0.f, 0.f, 0.f};
    const float* base = feats + (size_t)n * NB_SZ * R_SZ + lc * 4;
    for (int ll = 0; ll < NB_SZ; ll++) {
        float al = alpha[g][ll];
        float4 pv = *(const float4*)(base + ll * R_SZ);
        a4.x += al * pv.x; a4.y += al * pv.y;
        a4.z += al * pv.z; a4.w += al * pv.w;
    }
    uint2 att = {cvtpk(a4.x, a4.y), cvtpk(a4.z, a4.w)};
    *(uint2*)(feat + (size_t)n * D_SZ + lc * 4) = att;

    const float* ib = i3d + (size_t)n * 1024 + lc * 8;
    float4 iv0 = *(const float4*)ib;
    float4 iv1 = *(const float4*)(ib + 4);
    uint4 pk = {cvtpk(iv0.x, iv0.y), cvtpk(iv0.z, iv0.w),
                cvtpk(iv1.x, iv1.y), cvtpk(iv1.z, iv1.w)};
    *(uint4*)(feat + (size_t)n * D_SZ + 512 + lc * 8) = pk;
}

// ---------------------------------------------------------------------------
// p[n, j] = feat[n,:] @ Wr_f-row(j); tile 64m x 64n, 512 threads (2m x 4n
// waves), BK=128, double-buffered. 320 blocks; traffic 189MB (was 377MB).
// A: feat bf16 via global_load_lds (pre-swizzled); B: Wrf fp32 reg-staged.
// ---------------------------------------------------------------------------
__global__ __launch_bounds__(512, 2) void k_pgemm_mfma(
    const unsigned short* __restrict__ feat,  // (1280, 1536) bf16
    const float* __restrict__ Wrf,            // (512, 3072) fp32
    float* __restrict__ p)                    // (1280, 1024) fp32
{
    __shared__ __align__(16) unsigned char As[2][64 * 256];  // 16 KB each
    __shared__ __align__(16) unsigned char Bs[2][64 * 256];  // 16 KB each

    // bijective XCD swizzle: 320 = 8*40; n-major within XCD for Wrf L2 reuse
    const int bx = blockIdx.x;
    const int wid = (bx & 7) * 40 + (bx >> 3);
    const int mb = wid % 20, nb = wid / 20;
    const int m0 = mb * 64, j0 = nb * 64;
    const int t = threadIdx.x;

    const int lane = t & 63, w = t >> 6;
    const int wrm = w >> 2, wcn = w & 3;          // wave: 32m x 16n
    const int l15 = lane & 15, lk = lane >> 4;

    int arow[2];
    arow[0] = wrm * 32 + l15; arow[1] = arow[0] + 16;
    const int brow = wcn * 16 + l15;              // 0..63

    const size_t brow_base = (j0 < 512) ? (size_t)j0 * 3072
                                        : ((size_t)(j0 - 512) * 3072 + 1536);

    float4 blo[2], bhi[2];
    f32x4 acc[2] = {};

    // A tile 64r x 128k bf16 = 1024 x 16B; cid = it*512+t: r=cid>>4, c=cid&15
#define PG_STAGE_A(BUF, K0) do { \
    _Pragma("unroll") \
    for (int it = 0; it < 2; it++) { \
        int cid = it * 512 + t; \
        int r = cid >> 4, c = cid & 15; \
        int gc = c ^ (r & 7); \
        gload_lds16(feat + (size_t)(m0 + r) * D_SZ + (K0) + gc * 8, \
                    &As[BUF][it * 8192 + (t & 448) * 16]); \
    } } while (0)

    // B tile 64r x 128k fp32: 1024 chunks of 8 elems; same cid map
#define PG_LOAD_B(K0) do { \
    _Pragma("unroll") \
    for (int it = 0; it < 2; it++) { \
        int cid = it * 512 + t; \
        int r = cid >> 4, c = cid & 15; \
        const float* src = Wrf + brow_base + (size_t)r * 3072 + (K0) + c * 8; \
        blo[it] = *(const float4*)src; \
        bhi[it] = *(const float4*)(src + 4); \
    } } while (0)

#define PG_WRITE_B(BUF) do { \
    _Pragma("unroll") \
    for (int it = 0; it < 2; it++) { \
        int cid = it * 512 + t; \
        int r = cid >> 4, c = cid & 15; \
        uint4 pk = {cvtpk(blo[it].x, blo[it].y), cvtpk(blo[it].z, blo[it].w), \
                    cvtpk(bhi[it].x, bhi[it].y), cvtpk(bhi[it].z, bhi[it].w)}; \
        *(uint4*)(&Bs[BUF][r * 256 + ((c ^ (r & 7)) << 4)]) = pk; \
    } } while (0)

#define PG_COMPUTE(BUF) do { \
    _Pragma("unroll") \
    for (int ks = 0; ks < 4; ks++) { \
        int c = ks * 4 + lk; \
        short8 a0 = *(const short8*)(&As[BUF][arow[0] * 256 + ((c ^ (arow[0] & 7)) << 4)]); \
        short8 a1 = *(const short8*)(&As[BUF][arow[1] * 256 + ((c ^ (arow[1] & 7)) << 4)]); \
        short8 bv = *(const short8*)(&Bs[BUF][brow * 256 + ((c ^ (brow & 7)) << 4)]); \
        acc[0] = __builtin_amdgcn_mfma_f32_16x16x32_bf16(a0, bv, acc[0], 0, 0, 0); \
        acc[1] = __builtin_amdgcn_mfma_f32_16x16x32_bf16(a1, bv, acc[1], 0, 0, 0); \
    } } while (0)

    PG_LOAD_B(0);
    PG_STAGE_A(0, 0);
    PG_WRITE_B(0);
    __syncthreads();

#pragma unroll
    for (int ki = 0; ki < 12; ki++) {
        const int cur = ki & 1;
        if (ki < 11) {
            PG_LOAD_B((ki + 1) * 128);
            PG_STAGE_A(cur ^ 1, (ki + 1) * 128);
        }
        PG_COMPUTE(cur);
        if (ki < 11) PG_WRITE_B(cur ^ 1);
        __syncthreads();
    }

#pragma unroll
    for (int i = 0; i < 2; i++)
#pragma unroll
        for (int q = 0; q < 4; q++) {
            int row = m0 + wrm * 32 + i * 16 + lk * 4 + q;
            int col = j0 + wcn * 16 + l15;
            p[(size_t)row * 1024 + col] = acc[i][q];
        }
#undef PG_STAGE_A
#undef PG_LOAD_B
#undef PG_WRITE_B
#undef PG_COMPUTE
}

// ---------------------------------------------------------------------------
// e2[b,i,j] = sum_d tanh(p2[b*F+i,d] + p1[b*F+j,d] + hr[b,d]) * war[d]
// block = (b, i-quad): 320 blocks x 256 threads; p1 rows staged once in LDS.
// ---------------------------------------------------------------------------
__global__ __launch_bounds__(256) void k_e2(
    const float* __restrict__ p,
    const float* __restrict__ hr,
    const float* __restrict__ war,
    float* __restrict__ e2)
{
    __shared__ float p1l[F_SZ][512];   // 80 KB
    const int blk = blockIdx.x;
    const int b = blk / 10, io = blk % 10;
    const int t = threadIdx.x;
    const int w = t >> 6, l = t & 63;

    // stage all 40 p1 rows of this b (fp32, exact)
#pragma unroll
    for (int u = 0; u < 10; u++) {
        int cid = u * 256 + t;
        int r = cid >> 6, c = cid & 63;
        const float* src = p + (size_t)(b * F_SZ + r) * 1024 + c * 8;
        *(float4*)&p1l[r][c * 8]     = *(const float4*)src;
        *(float4*)&p1l[r][c * 8 + 4] = *(const float4*)(src + 4);
    }

    const int i = io * 4 + w;
    const int ni = b * F_SZ + i;
    float base[8], warf[8];
    {
        float4 pa = *(const float4*)(p + (size_t)ni * 1024 + 512 + l * 8);
        float4 pb = *(const float4*)(p + (size_t)ni * 1024 + 512 + l * 8 + 4);
        float4 ha = *(const float4*)(hr + b * H_SZ + l * 8);
        float4 hb = *(const float4*)(hr + b * H_SZ + l * 8 + 4);
        base[0] = pa.x + ha.x; base[1] = pa.y + ha.y; base[2] = pa.z + ha.z; base[3] = pa.w + ha.w;
        base[4] = pb.x + hb.x; base[5] = pb.y + hb.y; base[6] = pb.z + hb.z; base[7] = pb.w + hb.w;
        float4 wa = *(const float4*)(war + l * 8);
        float4 wb = *(const float4*)(war + l * 8 + 4);
        warf[0] = wa.x; warf[1] = wa.y; warf[2] = wa.z; warf[3] = wa.w;
        warf[4] = wb.x; warf[5] = wb.y; warf[6] = wb.z; warf[7] = wb.w;
    }
    __syncthreads();

    for (int j = 0; j < F_SZ; j++) {
        const float* r = p1l[j];
        float4 va = *(const float4*)(r + l * 8);
        float4 vb = *(const float4*)(r + l * 8 + 4);
        float pv[8] = {va.x, va.y, va.z, va.w, vb.x, vb.y, vb.z, vb.w};
        float s = 0.f;
#pragma unroll
        for (int u = 0; u < 8; u++) s += fast_tanh(pv[u] + base[u]) * warf[u];
#pragma unroll
        for (int off = 32; off; off >>= 1) s += __shfl_xor(s, off);
        if (l == 0) e2[(size_t)b * 1600 + i * F_SZ + j] = s;
    }
}

// ---------------------------------------------------------------------------
// per (b, third): softmax over 1600 e2's (redundant per third), rowsum/colsum,
// weighted feat sums over 512 columns (FP32 OUT). 96 blocks.
// ---------------------------------------------------------------------------
__global__ __launch_bounds__(256) void k_out(
    const float* __restrict__ e2,
    const unsigned short* __restrict__ feat,
    float* __restrict__ out)                   // (32, 3072) FP32
{
    __shared__ float alpha[1600];
    __shared__ float red[4];
    __shared__ float rs[F_SZ], cs[F_SZ];
    const int b = blockIdx.x / 3, third = blockIdx.x % 3;
    const int t = threadIdx.x;
    const int w = t >> 6, l = t & 63;

    float lm = -1e30f;
    for (int idx = t; idx < 1600; idx += 256) {
        float v = e2[(size_t)b * 1600 + idx];
        alpha[idx] = v;
        lm = fmaxf(lm, v);
    }
#pragma unroll
    for (int off = 32; off; off >>= 1) lm = fmaxf(lm, __shfl_xor(lm, off));
    if (l == 0) red[w] = lm;
    __syncthreads();
    float M = fmaxf(fmaxf(red[0], red[1]), fmaxf(red[2], red[3]));
    __syncthreads();
    float ls = 0.f;
    for (int idx = t; idx < 1600; idx += 256) {
        float ex = __expf(alpha[idx] - M);
        alpha[idx] = ex;
        ls += ex;
    }
#pragma unroll
    for (int off = 32; off; off >>= 1) ls += __shfl_xor(ls, off);
    if (l == 0) red[w] = ls;
    __syncthreads();
    float inv = 1.f / (red[0] + red[1] + red[2] + red[3]);

    if (t < F_SZ) {
        float s = 0.f;
        for (int j = 0; j < F_SZ; j++) s += alpha[t * F_SZ + j];
        rs[t] = s * inv;
    } else if (t >= 128 && t < 128 + F_SZ) {
        int j = t - 128;
        float s = 0.f;
        for (int i2 = 0; i2 < F_SZ; i2++) s += alpha[i2 * F_SZ + j];
        cs[j] = s * inv;
    }
    __syncthreads();

    const int cb = third * 512;
    float a1[2] = {0.f, 0.f};
    float a2[2] = {0.f, 0.f};
    for (int r = 0; r < F_SZ; r++) {
        float w1 = cs[r], w2 = rs[r];
        const unsigned short* fr = feat + (size_t)(b * F_SZ + r) * D_SZ + cb;
#pragma unroll
        for (int u = 0; u < 2; u++) {
            float f = bf2f(fr[t + u * 256]);
            a1[u] += w1 * f;
            a2[u] += w2 * f;
        }
    }
#pragma unroll
    for (int u = 0; u < 2; u++) {
        out[(size_t)b * 3072 + cb + t + u * 256]        = a1[u];
        out[(size_t)b * 3072 + 1536 + cb + t + u * 256] = a2[u];
    }
}

// ---------------------------------------------------------------------------
// Workspace layout (9,510,912 B total):
//   0        hs   (64 KB)
//   65536    hr   (64 KB)
//   131072   p    (5,242,880)  -- also hosts, before pgemm writes it:
//              e1p at 131072 (368,640; dead after k_softatt)
//              Wsb at 4849664 (524,288; dead after k_e1_mfma)
//   5373952  e2   (204,800)
//   5578752  feat (3,932,160)
// ---------------------------------------------------------------------------
extern "C" void kernel_launch(void* const* d_in, const int* in_sizes, int n_in,
                              void* d_out, int out_size, void* d_ws, size_t ws_size,
                              hipStream_t stream) {
    const float* i3d    = (const float*)d_in[0];
    const float* objf   = (const float*)d_in[1];
    const float* hidden = (const float*)d_in[2];
    const float* Wsf    = (const float*)d_in[3];
    const float* bsf    = (const float*)d_in[4];
    const float* Wsh    = (const float*)d_in[5];
    const float* bsh    = (const float*)d_in[6];
    const float* was    = (const float*)d_in[7];
    const float* Wrf    = (const float*)d_in[8];
    const float* brf    = (const float*)d_in[9];
    const float* Wrh    = (const float*)d_in[10];
    const float* brh    = (const float*)d_in[11];
    const float* war    = (const float*)d_in[12];
    float* out = (float*)d_out;

    char* ws = (char*)d_ws;
    float* hs  = (float*)(ws);
    float* hr  = (float*)(ws + 65536);
    float* p   = (float*)(ws + 131072);
    float* e1p = (float*)(ws + 131072);                     // inside p (dead before pgemm)
    unsigned short* Wsb = (unsigned short*)(ws + 4849664);  // inside p tail
    float* e2  = (float*)(ws + 5373952);
    unsigned short* feat = (unsigned short*)(ws + 5578752);

    k_pre<<<dim3(384), dim3(256), 0, stream>>>(hidden, Wsh, bsh, bsf, Wrh, brh, brf, hs, hr, Wsf, Wsb);
    k_e1_mfma<<<dim3(720), dim3(512), 0, stream>>>(objf, Wsb, was, hs, e1p);
    k_softatt<<<dim3(640), dim3(256), 0, stream>>>(objf, i3d, e1p, feat);
    k_pgemm_mfma<<<dim3(320), dim3(512), 0, stream>>>(feat, Wrf, p);
    k_e2<<<dim3(320), dim3(256), 0, stream>>>(p, hr, war, e2);
    k_out<<<dim3(96), dim3(256), 0, stream>>>(e2, feat, out);
}

// Round 7
// 262.923 us; speedup vs baseline: 1.0679x; 1.0679x over previous
//
#include <hip/hip_runtime.h>
#include <stdint.h>

// Problem constants
#define B_SZ 32
#define F_SZ 40
#define NB_SZ 36
#define R_SZ 512
#define H_SZ 512
#define D_SZ 1536
#define M1 (B_SZ * F_SZ * NB_SZ)   // 46080
#define NROW (B_SZ * F_SZ)         // 1280
#define FNB (F_SZ * NB_SZ)         // 1440

typedef __attribute__((ext_vector_type(8))) short short8;   // 8 bf16 (MFMA A/B frag)
typedef __attribute__((ext_vector_type(4))) float f32x4;    // MFMA C/D frag

__device__ __forceinline__ unsigned short f2bf(float f) {
    unsigned int x = __float_as_uint(f);
    return (unsigned short)((x + 0x7fffu + ((x >> 16) & 1u)) >> 16);  // RNE
}
__device__ __forceinline__ float bf2f(unsigned short u) {
    union { unsigned int i; float f; } v; v.i = ((unsigned int)u) << 16; return v.f;
}
__device__ __forceinline__ unsigned int cvtpk(float lo, float hi) {
    unsigned int r;
    asm("v_cvt_pk_bf16_f32 %0, %1, %2" : "=v"(r) : "v"(lo), "v"(hi));
    return r;
}
__device__ __forceinline__ float fast_rcp(float x) {
    float r; asm("v_rcp_f32 %0, %1" : "=v"(r) : "v"(x)); return r;
}
// tanh(x) = 1 - 2/(exp2(2*log2e*x)+1). Saturates correctly at +/-inf exp2.
__device__ __forceinline__ float fast_tanh(float x) {
    float t = __builtin_amdgcn_exp2f(2.8853900817779268f * x);
    return 1.0f - 2.0f * fast_rcp(t + 1.0f);
}

// direct-to-LDS 16B DMA: wave-uniform LDS base + lane*16; per-lane global src
__device__ __forceinline__ void gload_lds16(const void* gsrc, void* ldst) {
    __builtin_amdgcn_global_load_lds(
        (const __attribute__((address_space(1))) unsigned int*)gsrc,
        (__attribute__((address_space(3))) unsigned int*)ldst, 16, 0, 0);
}

// ---------------------------------------------------------------------------
// merged: blocks 0..255 -> hproj; blocks 256..383 -> Wsb = bf16(Wsf)
// ---------------------------------------------------------------------------
__global__ __launch_bounds__(256) void k_pre(
    const float* __restrict__ hidden,
    const float* __restrict__ Wsh, const float* __restrict__ bsh,
    const float* __restrict__ bsf,
    const float* __restrict__ Wrh, const float* __restrict__ brh,
    const float* __restrict__ brf,
    float* __restrict__ hs, float* __restrict__ hr,
    const float* __restrict__ Wsf, unsigned short* __restrict__ Wsb)
{
    const int t = threadIdx.x;
    if (blockIdx.x >= 256) {
        int i = ((blockIdx.x - 256) * 256 + t) * 8;
        float4 f0 = *(const float4*)(Wsf + i);
        float4 f1 = *(const float4*)(Wsf + i + 4);
        uint4 pk = {cvtpk(f0.x, f0.y), cvtpk(f0.z, f0.w),
                    cvtpk(f1.x, f1.y), cvtpk(f1.z, f1.w)};
        *(uint4*)(Wsb + i) = pk;
        return;
    }
    __shared__ float hid[H_SZ];
    const int b = blockIdx.x >> 3, hc = blockIdx.x & 7;
    for (int i = t; i < H_SZ; i += 256) hid[i] = hidden[b * H_SZ + i];
    __syncthreads();
    const int h = hc * 64 + (t >> 2), kq = t & 3;
    const float* r1 = Wsh + (size_t)h * H_SZ + kq * 128;
    const float* r2 = Wrh + (size_t)h * H_SZ + kq * 128;
    const float* hh = hid + kq * 128;
    float a1 = 0.f, a2 = 0.f;
    for (int k = 0; k < 128; k += 4) {
        float4 v1 = *(const float4*)(r1 + k);
        float4 v2 = *(const float4*)(r2 + k);
        a1 += hh[k] * v1.x + hh[k+1] * v1.y + hh[k+2] * v1.z + hh[k+3] * v1.w;
        a2 += hh[k] * v2.x + hh[k+1] * v2.y + hh[k+2] * v2.z + hh[k+3] * v2.w;
    }
    a1 += __shfl_xor(a1, 1); a1 += __shfl_xor(a1, 2);
    a2 += __shfl_xor(a2, 1); a2 += __shfl_xor(a2, 2);
    if (kq == 0) {
        hs[b * H_SZ + h] = a1 + bsh[h] + bsf[h];
        hr[b * H_SZ + h] = a2 + brh[h] + brf[h];
    }
}

// ---------------------------------------------------------------------------
// e1 partials: block = 64 m x 256 h (by-half), 256 thr, K-outer (8 x BK=64),
// hp-subtiles of 128 h. R5 structure (measured best) + counted-vmcnt raw
// barriers (A-loads stay in flight across phase-1 barrier) + setprio on MFMA.
// e1p[by][m] = sum_{h in half} tanh(S[m,h] + hs[b(m),h]) * was[h]
// ---------------------------------------------------------------------------
__global__ __launch_bounds__(256, 3) void k_e1_mfma(
    const float* __restrict__ feats,        // (46080, 512) fp32
    const unsigned short* __restrict__ Wsb, // (512, 512) bf16
    const float* __restrict__ was,
    const float* __restrict__ hs,
    float* __restrict__ e1p)                // (2, 46080) fp32
{
    __shared__ __align__(16) unsigned char As[2][64 * 128];    // 8 KB each
    __shared__ __align__(16) unsigned char Bs[2][128 * 128];   // 16 KB each
    __shared__ float hsl[2][256];
    __shared__ float wasl[256];
    __shared__ float eps[2][64];

    // bijective XCD swizzle: 1440 = 8*180; by-siblings adjacent on one XCD
    const int bx = blockIdx.x;
    const int wid = (bx & 7) * 180 + (bx >> 3);
    const int mb = wid >> 1, by = wid & 1;
    const int m0 = mb * 64, hb = by * 256;
    const int t = threadIdx.x;
    const int b0 = m0 / FNB, b1 = (m0 + 63) / FNB;
    const int thr = (b0 + 1) * FNB - m0;   // local rows >= thr belong to b1

    hsl[0][t] = hs[b0 * H_SZ + hb + t];
    hsl[1][t] = hs[b1 * H_SZ + hb + t];
    wasl[t]   = was[hb + t];

    const int lane = t & 63, w = t >> 6;
    const int wr = w >> 1, wc = w & 1;     // wave: 32m (wr) x 64h (wc) per hp
    const int l15 = lane & 15, lk = lane >> 4;

    int ar[2], brw[4];
#pragma unroll
    for (int i = 0; i < 2; i++) ar[i] = wr * 32 + i * 16 + l15;
#pragma unroll
    for (int j = 0; j < 4; j++) brw[j] = wc * 64 + j * 16 + l15;

    const int srow = t >> 3;          // 0..31
    const int scol = t & 7;           // 16B chunk within 64-k row
    const int wub  = (t & 192) * 16;  // wave-uniform LDS sub-base

    float4 alo[2], ahi[2];
    f32x4 acc[2][8] = {};
    float ep[2][4] = {{0.f}};

    // A tile 64x64 fp32: 512 chunks of 8; cid = it*256+t, it<2  -> 4 loads
#define E1_LOAD_A(K0) do { \
    _Pragma("unroll") \
    for (int it = 0; it < 2; it++) { \
        int cid = it * 256 + t; \
        int r = cid >> 3, c = cid & 7; \
        const float* src = feats + (size_t)(m0 + r) * R_SZ + (K0) + c * 8; \
        alo[it] = *(const float4*)src; \
        ahi[it] = *(const float4*)(src + 4); \
    } } while (0)

#define E1_WRITE_A(AB) do { \
    _Pragma("unroll") \
    for (int it = 0; it < 2; it++) { \
        int cid = it * 256 + t; \
        int r = cid >> 3, c = cid & 7; \
        uint4 pk = {cvtpk(alo[it].x, alo[it].y), cvtpk(alo[it].z, alo[it].w), \
                    cvtpk(ahi[it].x, ahi[it].y), cvtpk(ahi[it].z, ahi[it].w)}; \
        *(uint4*)(&As[AB][r * 128 + ((c ^ (r & 7)) << 4)]) = pk; \
    } } while (0)

    // B tile 128h x 64k bf16: 1024 x 16B chunks; it 0..3 -> 4 DMA
#define E1_STAGE_B(BUF, HP, K0) do { \
    _Pragma("unroll") \
    for (int it = 0; it < 4; it++) { \
        int r = it * 32 + srow; \
        int gc = scol ^ (r & 7); \
        gload_lds16(Wsb + (size_t)(hb + (HP) * 128 + r) * R_SZ + (K0) + gc * 8, \
                    &Bs[BUF][it * 4096 + wub]); \
    } } while (0)

#define E1_COMPUTE(HP, BB, AB) do { \
    __builtin_amdgcn_s_setprio(1); \
    _Pragma("unroll") \
    for (int ks = 0; ks < 2; ks++) { \
        short8 a[2], bv[4]; \
        int c = ks * 4 + lk; \
        _Pragma("unroll") \
        for (int i = 0; i < 2; i++) \
            a[i] = *(const short8*)(&As[AB][ar[i] * 128 + ((c ^ (ar[i] & 7)) << 4)]); \
        _Pragma("unroll") \
        for (int j = 0; j < 4; j++) \
            bv[j] = *(const short8*)(&Bs[BB][brw[j] * 128 + ((c ^ (brw[j] & 7)) << 4)]); \
        _Pragma("unroll") \
        for (int i = 0; i < 2; i++) \
        _Pragma("unroll") \
        for (int j = 0; j < 4; j++) \
            acc[i][(HP) * 4 + j] = __builtin_amdgcn_mfma_f32_16x16x32_bf16( \
                a[i], bv[j], acc[i][(HP) * 4 + j], 0, 0, 0); \
    } \
    __builtin_amdgcn_s_setprio(0); \
    } while (0)

    // prologue: A(ki=0) issued FIRST (older), then B(ki=0,hp=0) DMA
    E1_LOAD_A(0);
    E1_STAGE_B(0, 0, 0);
    E1_WRITE_A(0);   // compiler waits A (vmcnt(4): B still in flight)
    asm volatile("s_waitcnt vmcnt(0) lgkmcnt(0)\ns_barrier" ::: "memory");

#pragma unroll
    for (int ki = 0; ki < 8; ki++) {
        const int ab = ki & 1;
        // ---- phase 1: B(hp1) DMA first (older), then A(next) loads ----
        E1_STAGE_B(1, 1, ki * 64);
        if (ki < 7) E1_LOAD_A((ki + 1) * 64);
        E1_COMPUTE(0, 0, ab);
        if (ki < 7) {
            // retire the 4 B-DMAs; keep the 4 A-loads in flight across barrier
            asm volatile("s_waitcnt vmcnt(4)\ns_barrier" ::: "memory");
        } else {
            asm volatile("s_waitcnt vmcnt(0)\ns_barrier" ::: "memory");
        }
        // ---- phase 2 ----
        if (ki < 7) E1_STAGE_B(0, 0, (ki + 1) * 64);  // next-ki hp0
        E1_COMPUTE(1, 1, ab);
        if (ki < 7) E1_WRITE_A(ab ^ 1);               // compiler-waits A-loads
        asm volatile("s_waitcnt vmcnt(0) lgkmcnt(0)\ns_barrier" ::: "memory");
    }

    // epilogue: tanh + was-weighted row partials over 256 h of this half
#pragma unroll
    for (int jj = 0; jj < 8; jj++) {
        int hl = (jj >> 2) * 128 + wc * 64 + (jj & 3) * 16 + l15;
        float wv = wasl[hl];
#pragma unroll
        for (int i = 0; i < 2; i++) {
#pragma unroll
            for (int q = 0; q < 4; q++) {
                int r = wr * 32 + i * 16 + lk * 4 + q;
                float hv = hsl[r >= thr ? 1 : 0][hl];
                ep[i][q] += fast_tanh(acc[i][jj][q] + hv) * wv;
            }
        }
    }
#pragma unroll
    for (int i = 0; i < 2; i++)
#pragma unroll
        for (int q = 0; q < 4; q++) {
            float v = ep[i][q];
            v += __shfl_xor(v, 1);
            v += __shfl_xor(v, 2);
            v += __shfl_xor(v, 4);
            v += __shfl_xor(v, 8);
            if (l15 == 0) eps[wc][wr * 32 + i * 16 + lk * 4 + q] = v;
        }
    __syncthreads();
    if (t < 64) e1p[(size_t)by * M1 + m0 + t] = eps[0][t] + eps[1][t];
#undef E1_LOAD_A
#undef E1_WRITE_A
#undef E1_STAGE_B
#undef E1_COMPUTE
}

// ---------------------------------------------------------------------------
// per n-pair: softmax over 36 e1's (2 partials), att = alpha-weighted sum of
// feats rows (float4 loads), feat[n] = [att(512) | i3d(1024)] bf16. 640 blocks.
// ---------------------------------------------------------------------------
__global__ __launch_bounds__(256) void k_softatt(
    const float* __restrict__ feats,
    const float* __restrict__ i3d,
    const float* __restrict__ e1p,
    unsigned short* __restrict__ feat)
{
    __shared__ float alpha[2][NB_SZ];
    const int n0 = blockIdx.x * 2;
    const int t = threadIdx.x;
    const int w = t >> 6;

    if (w < 2) {
        const int n = n0 + w, lane = t & 63;
        float v = -1e30f;
        if (lane < NB_SZ) {
            int idx = n * NB_SZ + lane;
            v = e1p[idx] + e1p[M1 + idx];
        }
        float m = v;
#pragma unroll
        for (int off = 32; off; off >>= 1) m = fmaxf(m, __shfl_xor(m, off));
        float ex = (lane < NB_SZ) ? __expf(v - m) : 0.f;
        float ssum = ex;
#pragma unroll
        for (int off = 32; off; off >>= 1) ssum += __shfl_xor(ssum, off);
        if (lane < NB_SZ) alpha[w][lane] = ex / ssum;
    }
    __syncthreads();

    const int g = t >> 7, lc = t & 127;
    const int n = n0 + g;
    float4 a4 = {0.f, 0.f, 0.f, 0.f};
    const float* base = feats + (size_t)n * NB_SZ * R_SZ + lc * 4;
    for (int ll = 0; ll < NB_SZ; ll++) {
        float al = alpha[g][ll];
        float4 pv = *(const float4*)(base + ll * R_SZ);
        a4.x += al * pv.x; a4.y += al * pv.y;
        a4.z += al * pv.z; a4.w += al * pv.w;
    }
    uint2 att = {cvtpk(a4.x, a4.y), cvtpk(a4.z, a4.w)};
    *(uint2*)(feat + (size_t)n * D_SZ + lc * 4) = att;

    const float* ib = i3d + (size_t)n * 1024 + lc * 8;
    float4 iv0 = *(const float4*)ib;
    float4 iv1 = *(const float4*)(ib + 4);
    uint4 pk = {cvtpk(iv0.x, iv0.y), cvtpk(iv0.z, iv0.w),
                cvtpk(iv1.x, iv1.y), cvtpk(iv1.z, iv1.w)};
    *(uint4*)(feat + (size_t)n * D_SZ + 512 + lc * 8) = pk;
}

// ---------------------------------------------------------------------------
// p[n, j] = feat[n,:] @ Wr_f-row(j); tile 64m x 32n, 256 thr (2m x 2n waves),
// BK=128, dbuf. 640 blocks (2.5/CU avg, 3/CU capacity at 48KB LDS).
// A: feat bf16 via global_load_lds (pre-swizzled); B: Wrf fp32 reg-staged.
// ---------------------------------------------------------------------------
__global__ __launch_bounds__(256) void k_pgemm_mfma(
    const unsigned short* __restrict__ feat,  // (1280, 1536) bf16
    const float* __restrict__ Wrf,            // (512, 3072) fp32
    float* __restrict__ p)                    // (1280, 1024) fp32
{
    __shared__ __align__(16) unsigned char As[2][64 * 256];  // 16 KB each
    __shared__ __align__(16) unsigned char Bs[2][32 * 256];  // 8 KB each

    // bijective XCD swizzle: 640 = 8*80; n-major within XCD for Wrf L2 reuse
    const int bx = blockIdx.x;
    const int wid = (bx & 7) * 80 + (bx >> 3);
    const int mb = wid % 20, nb = wid / 20;
    const int m0 = mb * 64, j0 = nb * 32;
    const int t = threadIdx.x;

    const int lane = t & 63, w = t >> 6;
    const int wrm = w >> 1, wcn = w & 1;          // wave: 32m x 16n
    const int l15 = lane & 15, lk = lane >> 4;

    int arow[2];
    arow[0] = wrm * 32 + l15; arow[1] = arow[0] + 16;
    const int brow = wcn * 16 + l15;              // 0..31

    const size_t brow_base = (j0 < 512) ? (size_t)j0 * 3072
                                        : ((size_t)(j0 - 512) * 3072 + 1536);

    float4 blo[2], bhi[2];
    f32x4 acc[2] = {};

    // A tile 64r x 128k bf16 = 1024 x 16B; cid = it*256+t: r=cid>>4, c=cid&15
#define PG_STAGE_A(BUF, K0) do { \
    _Pragma("unroll") \
    for (int it = 0; it < 4; it++) { \
        int cid = it * 256 + t; \
        int r = cid >> 4, c = cid & 15; \
        int gc = c ^ (r & 7); \
        gload_lds16(feat + (size_t)(m0 + r) * D_SZ + (K0) + gc * 8, \
                    &As[BUF][it * 4096 + (t & 192) * 16]); \
    } } while (0)

    // B tile 32r x 128k fp32: 512 chunks of 8; cid = it*256+t: r=cid>>4, c=cid&15
#define PG_LOAD_B(K0) do { \
    _Pragma("unroll") \
    for (int it = 0; it < 2; it++) { \
        int cid = it * 256 + t; \
        int r = cid >> 4, c = cid & 15; \
        const float* src = Wrf + brow_base + (size_t)r * 3072 + (K0) + c * 8; \
        blo[it] = *(const float4*)src; \
        bhi[it] = *(const float4*)(src + 4); \
    } } while (0)

#define PG_WRITE_B(BUF) do { \
    _Pragma("unroll") \
    for (int it = 0; it < 2; it++) { \
        int cid = it * 256 + t; \
        int r = cid >> 4, c = cid & 15; \
        uint4 pk = {cvtpk(blo[it].x, blo[it].y), cvtpk(blo[it].z, blo[it].w), \
                    cvtpk(bhi[it].x, bhi[it].y), cvtpk(bhi[it].z, bhi[it].w)}; \
        *(uint4*)(&Bs[BUF][r * 256 + ((c ^ (r & 7)) << 4)]) = pk; \
    } } while (0)

#define PG_COMPUTE(BUF) do { \
    __builtin_amdgcn_s_setprio(1); \
    _Pragma("unroll") \
    for (int ks = 0; ks < 4; ks++) { \
        int c = ks * 4 + lk; \
        short8 a0 = *(const short8*)(&As[BUF][arow[0] * 256 + ((c ^ (arow[0] & 7)) << 4)]); \
        short8 a1 = *(const short8*)(&As[BUF][arow[1] * 256 + ((c ^ (arow[1] & 7)) << 4)]); \
        short8 bv = *(const short8*)(&Bs[BUF][brow * 256 + ((c ^ (brow & 7)) << 4)]); \
        acc[0] = __builtin_amdgcn_mfma_f32_16x16x32_bf16(a0, bv, acc[0], 0, 0, 0); \
        acc[1] = __builtin_amdgcn_mfma_f32_16x16x32_bf16(a1, bv, acc[1], 0, 0, 0); \
    } \
    __builtin_amdgcn_s_setprio(0); \
    } while (0)

    PG_LOAD_B(0);
    PG_STAGE_A(0, 0);
    PG_WRITE_B(0);
    __syncthreads();

#pragma unroll
    for (int ki = 0; ki < 12; ki++) {
        const int cur = ki & 1;
        if (ki < 11) {
            PG_LOAD_B((ki + 1) * 128);
            PG_STAGE_A(cur ^ 1, (ki + 1) * 128);
        }
        PG_COMPUTE(cur);
        if (ki < 11) PG_WRITE_B(cur ^ 1);
        __syncthreads();
    }

#pragma unroll
    for (int i = 0; i < 2; i++)
#pragma unroll
        for (int q = 0; q < 4; q++) {
            int row = m0 + wrm * 32 + i * 16 + lk * 4 + q;
            int col = j0 + wcn * 16 + l15;
            p[(size_t)row * 1024 + col] = acc[i][q];
        }
#undef PG_STAGE_A
#undef PG_LOAD_B
#undef PG_WRITE_B
#undef PG_COMPUTE
}

// ---------------------------------------------------------------------------
// e2[b,i,j] = sum_d tanh(p2[b*F+i,d] + p1[b*F+j,d] + hr[b,d]) * war[d]
// block = (b, i-quad): 320 blocks x 256 threads; p1 rows staged once in LDS.
// ---------------------------------------------------------------------------
__global__ __launch_bounds__(256) void k_e2(
    const float* __restrict__ p,
    const float* __restrict__ hr,
    const float* __restrict__ war,
    float* __restrict__ e2)
{
    __shared__ float p1l[F_SZ][512];   // 80 KB
    const int blk = blockIdx.x;
    const int b = blk / 10, io = blk % 10;
    const int t = threadIdx.x;
    const int w = t >> 6, l = t & 63;

    // stage all 40 p1 rows of this b (fp32, exact)
#pragma unroll
    for (int u = 0; u < 10; u++) {
        int cid = u * 256 + t;
        int r = cid >> 6, c = cid & 63;
        const float* src = p + (size_t)(b * F_SZ + r) * 1024 + c * 8;
        *(float4*)&p1l[r][c * 8]     = *(const float4*)src;
        *(float4*)&p1l[r][c * 8 + 4] = *(const float4*)(src + 4);
    }

    const int i = io * 4 + w;
    const int ni = b * F_SZ + i;
    float base[8], warf[8];
    {
        float4 pa = *(const float4*)(p + (size_t)ni * 1024 + 512 + l * 8);
        float4 pb = *(const float4*)(p + (size_t)ni * 1024 + 512 + l * 8 + 4);
        float4 ha = *(const float4*)(hr + b * H_SZ + l * 8);
        float4 hb = *(const float4*)(hr + b * H_SZ + l * 8 + 4);
        base[0] = pa.x + ha.x; base[1] = pa.y + ha.y; base[2] = pa.z + ha.z; base[3] = pa.w + ha.w;
        base[4] = pb.x + hb.x; base[5] = pb.y + hb.y; base[6] = pb.z + hb.z; base[7] = pb.w + hb.w;
        float4 wa = *(const float4*)(war + l * 8);
        float4 wb = *(const float4*)(war + l * 8 + 4);
        warf[0] = wa.x; warf[1] = wa.y; warf[2] = wa.z; warf[3] = wa.w;
        warf[4] = wb.x; warf[5] = wb.y; warf[6] = wb.z; warf[7] = wb.w;
    }
    __syncthreads();

    for (int j = 0; j < F_SZ; j++) {
        const float* r = p1l[j];
        float4 va = *(const float4*)(r + l * 8);
        float4 vb = *(const float4*)(r + l * 8 + 4);
        float pv[8] = {va.x, va.y, va.z, va.w, vb.x, vb.y, vb.z, vb.w};
        float s = 0.f;
#pragma unroll
        for (int u = 0; u < 8; u++) s += fast_tanh(pv[u] + base[u]) * warf[u];
#pragma unroll
        for (int off = 32; off; off >>= 1) s += __shfl_xor(s, off);
        if (l == 0) e2[(size_t)b * 1600 + i * F_SZ + j] = s;
    }
}

// ---------------------------------------------------------------------------
// per (b, sixth): softmax over 1600 e2's (redundant), rowsum/colsum, weighted
// feat sums over 256 columns (FP32 OUT). 192 blocks.
// ---------------------------------------------------------------------------
__global__ __launch_bounds__(256) void k_out(
    const float* __restrict__ e2,
    const unsigned short* __restrict__ feat,
    float* __restrict__ out)                   // (32, 3072) FP32
{
    __shared__ float alpha[1600];
    __shared__ float red[4];
    __shared__ float rs[F_SZ], cs[F_SZ];
    const int b = blockIdx.x / 6, sx = blockIdx.x % 6;
    const int t = threadIdx.x;
    const int w = t >> 6, l = t & 63;

    float lm = -1e30f;
    for (int idx = t; idx < 1600; idx += 256) {
        float v = e2[(size_t)b * 1600 + idx];
        alpha[idx] = v;
        lm = fmaxf(lm, v);
    }
#pragma unroll
    for (int off = 32; off; off >>= 1) lm = fmaxf(lm, __shfl_xor(lm, off));
    if (l == 0) red[w] = lm;
    __syncthreads();
    float M = fmaxf(fmaxf(red[0], red[1]), fmaxf(red[2], red[3]));
    __syncthreads();
    float ls = 0.f;
    for (int idx = t; idx < 1600; idx += 256) {
        float ex = __expf(alpha[idx] - M);
        alpha[idx] = ex;
        ls += ex;
    }
#pragma unroll
    for (int off = 32; off; off >>= 1) ls += __shfl_xor(ls, off);
    if (l == 0) red[w] = ls;
    __syncthreads();
    float inv = 1.f / (red[0] + red[1] + red[2] + red[3]);

    if (t < F_SZ) {
        float s = 0.f;
        for (int j = 0; j < F_SZ; j++) s += alpha[t * F_SZ + j];
        rs[t] = s * inv;
    } else if (t >= 128 && t < 128 + F_SZ) {
        int j = t - 128;
        float s = 0.f;
        for (int i2 = 0; i2 < F_SZ; i2++) s += alpha[i2 * F_SZ + j];
        cs[j] = s * inv;
    }
    __syncthreads();

    const int cb = sx * 256;
    float a1 = 0.f, a2 = 0.f;
    for (int r = 0; r < F_SZ; r++) {
        float w1 = cs[r], w2 = rs[r];
        float f = bf2f(feat[(size_t)(b * F_SZ + r) * D_SZ + cb + t]);
        a1 += w1 * f;
        a2 += w2 * f;
    }
    out[(size_t)b * 3072 + cb + t]        = a1;
    out[(size_t)b * 3072 + 1536 + cb + t] = a2;
}

// ---------------------------------------------------------------------------
// Workspace layout (9,510,912 B total):
//   0        hs   (64 KB)
//   65536    hr   (64 KB)
//   131072   p    (5,242,880)  -- also hosts, before pgemm writes it:
//              e1p at 131072 (368,640; dead after k_softatt)
//              Wsb at 4849664 (524,288; dead after k_e1_mfma)
//   5373952  e2   (204,800)
//   5578752  feat (3,932,160)
// ---------------------------------------------------------------------------
extern "C" void kernel_launch(void* const* d_in, const int* in_sizes, int n_in,
                              void* d_out, int out_size, void* d_ws, size_t ws_size,
                              hipStream_t stream) {
    const float* i3d    = (const float*)d_in[0];
    const float* objf   = (const float*)d_in[1];
    const float* hidden = (const float*)d_in[2];
    const float* Wsf    = (const float*)d_in[3];
    const float* bsf    = (const float*)d_in[4];
    const float* Wsh    = (const float*)d_in[5];
    const float* bsh    = (const float*)d_in[6];
    const float* was    = (const float*)d_in[7];
    const float* Wrf    = (const float*)d_in[8];
    const float* brf    = (const float*)d_in[9];
    const float* Wrh    = (const float*)d_in[10];
    const float* brh    = (const float*)d_in[11];
    const float* war    = (const float*)d_in[12];
    float* out = (float*)d_out;

    char* ws = (char*)d_ws;
    float* hs  = (float*)(ws);
    float* hr  = (float*)(ws + 65536);
    float* p   = (float*)(ws + 131072);
    float* e1p = (float*)(ws + 131072);                     // inside p (dead before pgemm)
    unsigned short* Wsb = (unsigned short*)(ws + 4849664);  // inside p tail
    float* e2  = (float*)(ws + 5373952);
    unsigned short* feat = (unsigned short*)(ws + 5578752);

    k_pre<<<dim3(384), dim3(256), 0, stream>>>(hidden, Wsh, bsh, bsf, Wrh, brh, brf, hs, hr, Wsf, Wsb);
    k_e1_mfma<<<dim3(1440), dim3(256), 0, stream>>>(objf, Wsb, was, hs, e1p);
    k_softatt<<<dim3(640), dim3(256), 0, stream>>>(objf, i3d, e1p, feat);
    k_pgemm_mfma<<<dim3(640), dim3(256), 0, stream>>>(feat, Wrf, p);
    k_e2<<<dim3(320), dim3(256), 0, stream>>>(p, hr, war, e2);
    k_out<<<dim3(192), dim3(256), 0, stream>>>(e2, feat, out);
}